// Round 5
// baseline (1770.234 us; speedup 1.0000x reference)
//
#include <hip/hip_runtime.h>
#include <hip/hip_bf16.h>

#define FDIM 256
#define FOUT 40

typedef __attribute__((ext_vector_type(8))) short short8;
typedef __attribute__((ext_vector_type(4))) float floatx4;

__device__ __forceinline__ float bf2f(unsigned short u) {
  unsigned int x = ((unsigned int)u) << 16;
  float f;
  __builtin_memcpy(&f, &x, 4);
  return f;
}
__device__ __forceinline__ unsigned short f2bf(float f) {
  __hip_bfloat16 h = __float2bfloat16(f);
  unsigned short u;
  __builtin_memcpy(&u, &h, 2);
  return u;
}

// ---------------- edge_index layout detection + normalization ----------------
// int64 little-endian with values < 2^31  =>  every odd 32-bit word is 0.

__global__ void detect_k(const int* __restrict__ raw, int nwords, int* __restrict__ flag) {
  if (threadIdx.x == 0) *flag = 0;
  __syncthreads();
  int found = 0;
  for (int w = 1 + 2 * threadIdx.x; w < nwords; w += 512)
    if (raw[w] != 0) { found = 1; break; }
  if (found) atomicOr(flag, 1);  // 1 => int32 layout
}

__global__ void normalize_k(const int* __restrict__ raw, const int* __restrict__ flag,
                            int* __restrict__ srcN, int* __restrict__ dstN, int e) {
  int i = blockIdx.x * 256 + threadIdx.x;
  if (i >= e) return;
  if (*flag) {
    srcN[i] = raw[i];
    dstN[i] = raw[e + i];
  } else {
    srcN[i] = raw[2 * i];
    dstN[i] = raw[2 * (e + i)];
  }
}

// ---------------- CSR build ----------------

__global__ void zero_cnt_k(int* cnt, int n) {
  int i = blockIdx.x * 256 + threadIdx.x;
  if (i < n) cnt[i] = 0;
}

__global__ void count_k(const int* __restrict__ dst, int* __restrict__ cnt, int e, int n) {
  int i = blockIdx.x * 256 + threadIdx.x;
  if (i < e) {
    int d = dst[i];
    if (d >= 0 && d < n) atomicAdd(&cnt[d], 1);
  }
}

__global__ void dis_k(const int* __restrict__ cnt, float* __restrict__ dis, int n) {
  int i = blockIdx.x * 256 + threadIdx.x;
  if (i < n) dis[i] = rsqrtf((float)cnt[i] + 1.0f);
}

__global__ void scan_a_k(const int* __restrict__ cnt, int* __restrict__ excl,
                         int* __restrict__ bsum, int n) {
  __shared__ int sh[1024];
  int t = threadIdx.x;
  int gid = blockIdx.x * 1024 + t;
  int v = (gid < n) ? cnt[gid] : 0;
  sh[t] = v;
  __syncthreads();
  for (int off = 1; off < 1024; off <<= 1) {
    int x = (t >= off) ? sh[t - off] : 0;
    __syncthreads();
    sh[t] += x;
    __syncthreads();
  }
  if (gid < n) excl[gid] = sh[t] - v;
  if (t == 1023) bsum[blockIdx.x] = sh[1023];
}

__global__ void scan_b_k(int* __restrict__ bsum, int nb) {
  __shared__ int sh[1024];
  int t = threadIdx.x;
  int v = (t < nb) ? bsum[t] : 0;
  sh[t] = v;
  __syncthreads();
  for (int off = 1; off < 1024; off <<= 1) {
    int x = (t >= off) ? sh[t - off] : 0;
    __syncthreads();
    sh[t] += x;
    __syncthreads();
  }
  if (t < nb) bsum[t] = sh[t] - v;
}

__global__ void scan_c_k(int* __restrict__ row_ptr, const int* __restrict__ bsum,
                         const int* __restrict__ cnt, int* __restrict__ cursor, int n) {
  int gid = blockIdx.x * 1024 + threadIdx.x;
  if (gid < n) {
    int r = row_ptr[gid] + bsum[blockIdx.x];
    row_ptr[gid] = r;
    cursor[gid] = r;
    if (gid == n - 1) row_ptr[n] = r + cnt[gid];
  }
}

__global__ void fill_k(const int* __restrict__ src, const int* __restrict__ dst,
                       int* __restrict__ cursor, int* __restrict__ col, int e, int n) {
  int i = blockIdx.x * 256 + threadIdx.x;
  if (i < e) {
    int d = dst[i];
    if (d >= 0 && d < n) {
      int slot = atomicAdd(&cursor[d], 1);
      int s = src[i];
      s = min(max(s, 0), n - 1);
      col[slot] = s;
    }
  }
}

// ---------------- W1T: bf16 transpose of fp32 W1 ----------------

__global__ void transp_k(const float* __restrict__ in, unsigned short* __restrict__ out) {
  out[(size_t)blockIdx.x * FDIM + threadIdx.x] =
      f2bf(in[(size_t)threadIdx.x * FDIM + blockIdx.x]);
}

// ---------------- Wc = W2 @ Wlin (fp32); bc = b2 @ Wlin + blin (fp32) ----------------

__global__ __launch_bounds__(64) void wc_k(const float* __restrict__ W2,
                                           const float* __restrict__ Wlin,
                                           float* __restrict__ Wc) {
  __shared__ float row[FDIM];
  int k = blockIdx.x, t = threadIdx.x;
  for (int j = t; j < FDIM; j += 64) row[j] = W2[(size_t)k * FDIM + j];
  __syncthreads();
  if (t < FOUT) {
    float acc = 0.f;
    for (int j = 0; j < FDIM; ++j) acc += row[j] * Wlin[(size_t)j * FOUT + t];
    Wc[(size_t)k * FOUT + t] = acc;
  }
}

__global__ __launch_bounds__(64) void bc_k(const float* __restrict__ b2,
                                           const float* __restrict__ Wlin,
                                           const float* __restrict__ blin,
                                           float* __restrict__ bc) {
  int t = threadIdx.x;
  if (t < FOUT) {
    float acc = blin[t];
    for (int j = 0; j < FDIM; ++j) acc += b2[j] * Wlin[(size_t)j * FOUT + t];
    bc[t] = acc;
  }
}

// ---------------- agg from x (fp32): out = bf16( dis_i*(x[i]*dis_i + sum x[src]*dis_src) ) ----------------

__global__ __launch_bounds__(256) void agg_x_k(
    const float* __restrict__ x, const int* __restrict__ row_ptr,
    const int* __restrict__ col, const float* __restrict__ dis,
    unsigned short* __restrict__ out, int n) {
  int wave = threadIdx.x >> 6, lane = threadIdx.x & 63;
  int wid = blockIdx.x * 4 + wave;
  int nw = gridDim.x * 4;
  for (int i = wid; i < n; i += nw) {
    int f = lane * 4;
    float di = dis[i];
    float4 v = *(const float4*)(x + (size_t)i * FDIM + f);
    float a0 = v.x * di, a1 = v.y * di, a2 = v.z * di, a3 = v.w * di;
    int beg = row_ptr[i], end = row_ptr[i + 1];
    for (int j0 = beg; j0 < end; j0 += 64) {
      int jj = j0 + lane;
      int cs = (jj < end) ? col[jj] : 0;
      float cd = (jj < end) ? dis[cs] : 0.f;
      int cc = min(64, end - j0);
      for (int k = 0; k < cc; ++k) {
        int s = __shfl(cs, k);
        float ds = __shfl(cd, k);
        float4 g = *(const float4*)(x + (size_t)s * FDIM + f);
        a0 += g.x * ds; a1 += g.y * ds; a2 += g.z * ds; a3 += g.w * ds;
      }
    }
    ushort4 o;
    o.x = f2bf(a0 * di); o.y = f2bf(a1 * di); o.z = f2bf(a2 * di); o.w = f2bf(a3 * di);
    *(ushort4*)(out + (size_t)i * FDIM + f) = o;
  }
}

// ---------------- in-place GEMM: buf = bf16( buf @ W1 + b1 ) ----------------

__global__ __launch_bounds__(256) void gemm_bias_k(
    const unsigned short* __restrict__ A, const unsigned short* __restrict__ BT,
    const float* __restrict__ bias, unsigned short* __restrict__ out, int M) {
  __shared__ __align__(16) unsigned short Asm[64 * 40];
  __shared__ __align__(16) unsigned short Bsm[256 * 40];
  int t = threadIdx.x;
  int block_m = blockIdx.x * 64;
  int lane = t & 63, wave = t >> 6;
  int q = lane >> 4, rcol = lane & 15;
  floatx4 acc[4][4] = {};

  for (int kk = 0; kk < 256; kk += 32) {
    __syncthreads();
    {
      int arow = t >> 2;
      int cc = (t & 3) * 8;
      uint4 v = {0, 0, 0, 0};
      int gm = block_m + arow;
      if (gm < M) v = *(const uint4*)(A + (size_t)gm * FDIM + kk + cc);
      *(uint4*)(Asm + arow * 40 + cc) = v;
#pragma unroll
      for (int it = 0; it < 4; ++it) {
        int brow = it * 64 + arow;
        uint4 wv = *(const uint4*)(BT + (size_t)brow * FDIM + kk + cc);
        *(uint4*)(Bsm + brow * 40 + cc) = wv;
      }
    }
    __syncthreads();
    short8 af[4], bfr[4];
#pragma unroll
    for (int mt = 0; mt < 4; ++mt)
      af[mt] = *(const short8*)(Asm + (mt * 16 + rcol) * 40 + q * 8);
#pragma unroll
    for (int nt = 0; nt < 4; ++nt)
      bfr[nt] = *(const short8*)(Bsm + (wave * 64 + nt * 16 + rcol) * 40 + q * 8);
#pragma unroll
    for (int mt = 0; mt < 4; ++mt)
#pragma unroll
      for (int nt = 0; nt < 4; ++nt)
        acc[mt][nt] = __builtin_amdgcn_mfma_f32_16x16x32_bf16(af[mt], bfr[nt], acc[mt][nt], 0, 0, 0);
  }

  float bv[4];
#pragma unroll
  for (int nt = 0; nt < 4; ++nt) bv[nt] = bias[wave * 64 + nt * 16 + rcol];
#pragma unroll
  for (int mt = 0; mt < 4; ++mt)
#pragma unroll
    for (int rr = 0; rr < 4; ++rr) {
      int m = block_m + mt * 16 + q * 4 + rr;
      if (m >= M) continue;
#pragma unroll
      for (int nt = 0; nt < 4; ++nt) {
        int nn = wave * 64 + nt * 16 + rcol;
        out[(size_t)m * FDIM + nn] = f2bf(acc[mt][nt][rr] + bv[nt]);
      }
    }
}

// ---------------- conv2 + head + log_softmax, fused; fp32 output ----------------

__global__ __launch_bounds__(256) void conv2_head_k(
    const unsigned short* __restrict__ l1, const int* __restrict__ row_ptr,
    const int* __restrict__ col, const float* __restrict__ dis,
    const float* __restrict__ Wc, const float* __restrict__ bc,
    float* __restrict__ out, int n) {
  __shared__ __align__(16) float Wsh[FDIM * FOUT];  // 40 KB fp32
  __shared__ __align__(16) float xsh[4][FDIM];
  __shared__ float L[4][FOUT];
  __shared__ float bsh[FOUT];
  int t = threadIdx.x;
  for (int c = t; c < FDIM * FOUT / 4; c += 256)
    ((uint4*)Wsh)[c] = ((const uint4*)Wc)[c];
  if (t < FOUT) bsh[t] = bc[t];
  int wave = t >> 6, lane = t & 63;
  int nd = t / 40, o = t - nd * 40;
  int step = gridDim.x * 4;
  for (int base = blockIdx.x * 4; base < n; base += step) {
    int i = base + wave;
    __syncthreads();
    if (i < n) {
      int f = lane * 4;
      float di = dis[i];
      float a0, a1, a2, a3;
      {
        ushort4 v = *(const ushort4*)(l1 + (size_t)i * FDIM + f);
        a0 = bf2f(v.x) * di; a1 = bf2f(v.y) * di; a2 = bf2f(v.z) * di; a3 = bf2f(v.w) * di;
      }
      int beg = row_ptr[i], end = row_ptr[i + 1];
      for (int j0 = beg; j0 < end; j0 += 64) {
        int jj = j0 + lane;
        int cs = (jj < end) ? col[jj] : 0;
        float cd = (jj < end) ? dis[cs] : 0.f;
        int cc = min(64, end - j0);
        for (int k = 0; k < cc; ++k) {
          int s = __shfl(cs, k);
          float ds = __shfl(cd, k);
          ushort4 v = *(const ushort4*)(l1 + (size_t)s * FDIM + f);
          a0 += bf2f(v.x) * ds; a1 += bf2f(v.y) * ds;
          a2 += bf2f(v.z) * ds; a3 += bf2f(v.w) * ds;
        }
      }
      float4 xv = {a0 * di, a1 * di, a2 * di, a3 * di};
      *(float4*)&xsh[wave][f] = xv;
    }
    __syncthreads();
    if (t < 160) {
      float acc = bsh[o];
      for (int k = 0; k < FDIM; ++k)
        acc += xsh[nd][k] * Wsh[k * FOUT + o];
      L[nd][o] = acc;
    }
    __syncthreads();
    if (t < 4) {
      int gi = base + t;
      if (gi < n) {
        float m = -3.4e38f;
        for (int oo = 0; oo < FOUT; ++oo) m = fmaxf(m, L[t][oo]);
        float s = 0.f;
        for (int oo = 0; oo < FOUT; ++oo) s += __expf(L[t][oo] - m);
        float lg = m + __logf(s);
        for (int oo = 0; oo < FOUT; ++oo)
          out[(size_t)gi * FOUT + oo] = L[t][oo] - lg;
      }
    }
  }
}

// ---------------- launch ----------------

extern "C" void kernel_launch(void* const* d_in, const int* in_sizes, int n_in,
                              void* d_out, int out_size, void* d_ws, size_t ws_size,
                              hipStream_t stream) {
  // fp32 inputs, fp32 output (reference output dtype is float32)
  const float* x   = (const float*)d_in[0];
  const int* eraw  = (const int*)d_in[1];
  const float* W1  = (const float*)d_in[2];
  const float* b1  = (const float*)d_in[3];
  const float* W2  = (const float*)d_in[4];
  const float* b2  = (const float*)d_in[5];
  const float* Wl  = (const float*)d_in[6];
  const float* bl  = (const float*)d_in[7];
  float* out = (float*)d_out;

  const int N = in_sizes[0] / FDIM;
  const int E = in_sizes[1] / 2;

  char* w = (char*)d_ws;
  size_t off = 0;
  auto take = [&](size_t bytes) {
    void* p = w + off;
    off = (off + bytes + 255) & ~(size_t)255;
    return p;
  };
  int* cnt     = (int*)take((size_t)N * 4);
  int* cursor  = (int*)take((size_t)N * 4);
  int* row_ptr = (int*)take((size_t)(N + 1) * 4);
  float* dis   = (float*)take((size_t)N * 4);
  int* bsum    = (int*)take(4096);
  int* eflag   = (int*)take(256);
  unsigned short* W1T = (unsigned short*)take((size_t)FDIM * FDIM * 2);
  float* Wc    = (float*)take((size_t)FDIM * FOUT * 4);
  float* bc    = (float*)take(FOUT * 4);
  int* colx    = (int*)take((size_t)E * 4);
  // union: srcN/dstN (CSR build) then buf (features)
  size_t unionBytes = (size_t)2 * E * 4;
  size_t bufBytes = (size_t)N * FDIM * 2;
  void* region = take(unionBytes > bufBytes ? unionBytes : bufBytes);
  int* srcN = (int*)region;
  int* dstN = srcN + E;
  unsigned short* buf = (unsigned short*)region;
  (void)ws_size; (void)n_in; (void)out_size;

  int gE = (E + 255) / 256;
  int gN = (N + 255) / 256;
  int NB = (N + 1023) / 1024;
  int gG = (N + 63) / 64;

  int probe_words = 65536 < 2 * E ? 65536 : 2 * E;
  hipLaunchKernelGGL(detect_k, dim3(1), dim3(256), 0, stream, eraw, probe_words, eflag);
  hipLaunchKernelGGL(normalize_k, dim3(gE), dim3(256), 0, stream, eraw, eflag, srcN, dstN, E);

  hipLaunchKernelGGL(zero_cnt_k, dim3(gN), dim3(256), 0, stream, cnt, N);
  hipLaunchKernelGGL(count_k, dim3(gE), dim3(256), 0, stream, dstN, cnt, E, N);
  hipLaunchKernelGGL(dis_k, dim3(gN), dim3(256), 0, stream, cnt, dis, N);
  hipLaunchKernelGGL(scan_a_k, dim3(NB), dim3(1024), 0, stream, cnt, row_ptr, bsum, N);
  hipLaunchKernelGGL(scan_b_k, dim3(1), dim3(1024), 0, stream, bsum, NB);
  hipLaunchKernelGGL(scan_c_k, dim3(NB), dim3(1024), 0, stream, row_ptr, bsum, cnt, cursor, N);
  hipLaunchKernelGGL(fill_k, dim3(gE), dim3(256), 0, stream, srcN, dstN, cursor, colx, E, N);
  hipLaunchKernelGGL(transp_k, dim3(FDIM), dim3(FDIM), 0, stream, W1, W1T);
  hipLaunchKernelGGL(wc_k, dim3(FDIM), dim3(64), 0, stream, W2, Wl, Wc);
  hipLaunchKernelGGL(bc_k, dim3(1), dim3(64), 0, stream, b2, Wl, bl, bc);

  // layer 1: buf = bf16(agg(x)); buf = buf @ W1 + b1 (in-place)
  hipLaunchKernelGGL(agg_x_k, dim3(2048), dim3(256), 0, stream,
                     x, row_ptr, colx, dis, buf, N);
  hipLaunchKernelGGL(gemm_bias_k, dim3(gG), dim3(256), 0, stream, buf, W1T, b1, buf, N);
  // conv2 + head + log_softmax fused, fp32 straight to d_out
  hipLaunchKernelGGL(conv2_head_k, dim3(2048), dim3(256), 0, stream,
                     buf, row_ptr, colx, dis, Wc, bc, out, N);
}

// Round 6
// 1184.910 us; speedup vs baseline: 1.4940x; 1.4940x over previous
//
#include <hip/hip_runtime.h>
#include <hip/hip_bf16.h>

#define FDIM 256
#define FOUT 40

typedef __attribute__((ext_vector_type(8))) short short8;
typedef __attribute__((ext_vector_type(4))) float floatx4;

__device__ __forceinline__ float bf2f(unsigned short u) {
  unsigned int x = ((unsigned int)u) << 16;
  float f;
  __builtin_memcpy(&f, &x, 4);
  return f;
}
__device__ __forceinline__ unsigned short f2bf(float f) {
  __hip_bfloat16 h = __float2bfloat16(f);
  unsigned short u;
  __builtin_memcpy(&u, &h, 2);
  return u;
}

// ---------------- edge_index layout detection + normalization ----------------

__global__ void detect_k(const int* __restrict__ raw, int nwords, int* __restrict__ flag) {
  if (threadIdx.x == 0) *flag = 0;
  __syncthreads();
  int found = 0;
  for (int w = 1 + 2 * threadIdx.x; w < nwords; w += 512)
    if (raw[w] != 0) { found = 1; break; }
  if (found) atomicOr(flag, 1);  // 1 => int32 layout
}

__global__ void normalize_k(const int* __restrict__ raw, const int* __restrict__ flag,
                            int* __restrict__ srcN, int* __restrict__ dstN, int e) {
  int i = blockIdx.x * 256 + threadIdx.x;
  if (i >= e) return;
  if (*flag) {
    srcN[i] = raw[i];
    dstN[i] = raw[e + i];
  } else {
    srcN[i] = raw[2 * i];
    dstN[i] = raw[2 * (e + i)];
  }
}

// ---------------- CSR build ----------------

__global__ void zero_cnt_k(int* cnt, int n) {
  int i = blockIdx.x * 256 + threadIdx.x;
  if (i < n) cnt[i] = 0;
}

__global__ void count_k(const int* __restrict__ dst, int* __restrict__ cnt, int e, int n) {
  int i = blockIdx.x * 256 + threadIdx.x;
  if (i < e) {
    int d = dst[i];
    if (d >= 0 && d < n) atomicAdd(&cnt[d], 1);
  }
}

__global__ void dis_k(const int* __restrict__ cnt, float* __restrict__ dis, int n) {
  int i = blockIdx.x * 256 + threadIdx.x;
  if (i < n) dis[i] = rsqrtf((float)cnt[i] + 1.0f);
}

__global__ void scan_a_k(const int* __restrict__ cnt, int* __restrict__ excl,
                         int* __restrict__ bsum, int n) {
  __shared__ int sh[1024];
  int t = threadIdx.x;
  int gid = blockIdx.x * 1024 + t;
  int v = (gid < n) ? cnt[gid] : 0;
  sh[t] = v;
  __syncthreads();
  for (int off = 1; off < 1024; off <<= 1) {
    int x = (t >= off) ? sh[t - off] : 0;
    __syncthreads();
    sh[t] += x;
    __syncthreads();
  }
  if (gid < n) excl[gid] = sh[t] - v;
  if (t == 1023) bsum[blockIdx.x] = sh[1023];
}

__global__ void scan_b_k(int* __restrict__ bsum, int nb) {
  __shared__ int sh[1024];
  int t = threadIdx.x;
  int v = (t < nb) ? bsum[t] : 0;
  sh[t] = v;
  __syncthreads();
  for (int off = 1; off < 1024; off <<= 1) {
    int x = (t >= off) ? sh[t - off] : 0;
    __syncthreads();
    sh[t] += x;
    __syncthreads();
  }
  if (t < nb) bsum[t] = sh[t] - v;
}

__global__ void scan_c_k(int* __restrict__ row_ptr, const int* __restrict__ bsum,
                         const int* __restrict__ cnt, int* __restrict__ cursor, int n) {
  int gid = blockIdx.x * 1024 + threadIdx.x;
  if (gid < n) {
    int r = row_ptr[gid] + bsum[blockIdx.x];
    row_ptr[gid] = r;
    cursor[gid] = r;
    if (gid == n - 1) row_ptr[n] = r + cnt[gid];
  }
}

__global__ void fill_k(const int* __restrict__ src, const int* __restrict__ dst,
                       int* __restrict__ cursor, int* __restrict__ col, int e, int n) {
  int i = blockIdx.x * 256 + threadIdx.x;
  if (i < e) {
    int d = dst[i];
    if (d >= 0 && d < n) {
      int slot = atomicAdd(&cursor[d], 1);
      int s = src[i];
      s = min(max(s, 0), n - 1);
      col[slot] = s;
    }
  }
}

// ---------------- W1T: bf16 transpose of fp32 W1 ----------------

__global__ void transp_k(const float* __restrict__ in, unsigned short* __restrict__ out) {
  out[(size_t)blockIdx.x * FDIM + threadIdx.x] =
      f2bf(in[(size_t)threadIdx.x * FDIM + blockIdx.x]);
}

// ---------------- Wc = W2 @ Wlin (fp32); bc = b2 @ Wlin + blin ----------------

__global__ __launch_bounds__(64) void wc_k(const float* __restrict__ W2,
                                           const float* __restrict__ Wlin,
                                           float* __restrict__ Wc) {
  __shared__ float row[FDIM];
  int k = blockIdx.x, t = threadIdx.x;
  for (int j = t; j < FDIM; j += 64) row[j] = W2[(size_t)k * FDIM + j];
  __syncthreads();
  if (t < FOUT) {
    float acc = 0.f;
    for (int j = 0; j < FDIM; ++j) acc += row[j] * Wlin[(size_t)j * FOUT + t];
    Wc[(size_t)k * FOUT + t] = acc;
  }
}

__global__ __launch_bounds__(64) void bc_k(const float* __restrict__ b2,
                                           const float* __restrict__ Wlin,
                                           const float* __restrict__ blin,
                                           float* __restrict__ bc) {
  int t = threadIdx.x;
  if (t < FOUT) {
    float acc = blin[t];
    for (int j = 0; j < FDIM; ++j) acc += b2[j] * Wlin[(size_t)j * FOUT + t];
    bc[t] = acc;
  }
}

// ---------------- xs = bf16(x * dis[row]) ----------------

__global__ __launch_bounds__(256) void fold_k(const float* __restrict__ x,
                                              const float* __restrict__ dis,
                                              unsigned short* __restrict__ xs, int n) {
  int total = n * (FDIM / 4);
  for (int idx = blockIdx.x * 256 + threadIdx.x; idx < total; idx += gridDim.x * 256) {
    int row = idx >> 6;
    float di = dis[row];
    float4 v = *(const float4*)(x + (size_t)idx * 4);
    ushort4 o;
    o.x = f2bf(v.x * di); o.y = f2bf(v.y * di); o.z = f2bf(v.z * di); o.w = f2bf(v.w * di);
    *(ushort4*)(xs + (size_t)idx * 4) = o;
  }
}

// ---------------- agg over bf16 pre-folded table: out = bf16( dis_i * (tab[i] + sum tab[src]) ) ----------------
// batched G=8 pipelined gathers; predicated tail via FMA weights

__global__ __launch_bounds__(256) void agg_b_k(
    const unsigned short* __restrict__ tab, const int* __restrict__ row_ptr,
    const int* __restrict__ col, const float* __restrict__ dis,
    unsigned short* __restrict__ out, int n) {
  int wave = threadIdx.x >> 6, lane = threadIdx.x & 63;
  int wid = blockIdx.x * 4 + wave;
  int nw = gridDim.x * 4;
  for (int i = wid; i < n; i += nw) {
    int f = lane * 4;
    ushort4 v = *(const ushort4*)(tab + (size_t)i * FDIM + f);
    float a0 = bf2f(v.x), a1 = bf2f(v.y), a2 = bf2f(v.z), a3 = bf2f(v.w);
    int beg = row_ptr[i], end = row_ptr[i + 1];
    for (int j0 = beg; j0 < end; j0 += 64) {
      int jj = j0 + lane;
      int cs = (jj < end) ? col[jj] : 0;
      int cc = min(64, end - j0);
      for (int k = 0; k < cc; k += 8) {
        ushort4 g[8];
        float w[8];
#pragma unroll
        for (int u = 0; u < 8; ++u) {
          int ku = k + u;
          int s = __shfl(cs, ku & 63);
          w[u] = (ku < cc) ? 1.f : 0.f;
          g[u] = *(const ushort4*)(tab + (size_t)s * FDIM + f);
        }
#pragma unroll
        for (int u = 0; u < 8; ++u) {
          a0 = fmaf(w[u], bf2f(g[u].x), a0);
          a1 = fmaf(w[u], bf2f(g[u].y), a1);
          a2 = fmaf(w[u], bf2f(g[u].z), a2);
          a3 = fmaf(w[u], bf2f(g[u].w), a3);
        }
      }
    }
    float di = dis[i];
    ushort4 o;
    o.x = f2bf(a0 * di); o.y = f2bf(a1 * di); o.z = f2bf(a2 * di); o.w = f2bf(a3 * di);
    *(ushort4*)(out + (size_t)i * FDIM + f) = o;
  }
}

// ---------------- fallback: agg over fp32 x with per-edge dis weight ----------------

__global__ __launch_bounds__(256) void agg_f_k(
    const float* __restrict__ x, const int* __restrict__ row_ptr,
    const int* __restrict__ col, const float* __restrict__ dis,
    unsigned short* __restrict__ out, int n) {
  int wave = threadIdx.x >> 6, lane = threadIdx.x & 63;
  int wid = blockIdx.x * 4 + wave;
  int nw = gridDim.x * 4;
  for (int i = wid; i < n; i += nw) {
    int f = lane * 4;
    float di = dis[i];
    float4 v = *(const float4*)(x + (size_t)i * FDIM + f);
    float a0 = v.x * di, a1 = v.y * di, a2 = v.z * di, a3 = v.w * di;
    int beg = row_ptr[i], end = row_ptr[i + 1];
    for (int j0 = beg; j0 < end; j0 += 64) {
      int jj = j0 + lane;
      int cs = (jj < end) ? col[jj] : 0;
      float cd = (jj < end) ? dis[cs] : 0.f;
      int cc = min(64, end - j0);
      for (int k = 0; k < cc; k += 8) {
        float4 g[8];
        float w[8];
#pragma unroll
        for (int u = 0; u < 8; ++u) {
          int ku = k + u;
          int s = __shfl(cs, ku & 63);
          float dv = __shfl(cd, ku & 63);
          w[u] = (ku < cc) ? dv : 0.f;
          g[u] = *(const float4*)(x + (size_t)s * FDIM + f);
        }
#pragma unroll
        for (int u = 0; u < 8; ++u) {
          a0 = fmaf(w[u], g[u].x, a0);
          a1 = fmaf(w[u], g[u].y, a1);
          a2 = fmaf(w[u], g[u].z, a2);
          a3 = fmaf(w[u], g[u].w, a3);
        }
      }
    }
    ushort4 o;
    o.x = f2bf(a0 * di); o.y = f2bf(a1 * di); o.z = f2bf(a2 * di); o.w = f2bf(a3 * di);
    *(ushort4*)(out + (size_t)i * FDIM + f) = o;
  }
}

// ---------------- in-place GEMM: buf = bf16( (buf @ W1 + b1) * dis[m] ) ----------------

__global__ __launch_bounds__(256) void gemm_bias_k(
    const unsigned short* __restrict__ A, const unsigned short* __restrict__ BT,
    const float* __restrict__ bias, const float* __restrict__ dis,
    unsigned short* __restrict__ out, int M) {
  __shared__ __align__(16) unsigned short Asm[64 * 40];
  __shared__ __align__(16) unsigned short Bsm[256 * 40];
  int t = threadIdx.x;
  int block_m = blockIdx.x * 64;
  int lane = t & 63, wave = t >> 6;
  int q = lane >> 4, rcol = lane & 15;
  floatx4 acc[4][4] = {};

  for (int kk = 0; kk < 256; kk += 32) {
    __syncthreads();
    {
      int arow = t >> 2;
      int cc = (t & 3) * 8;
      uint4 v = {0, 0, 0, 0};
      int gm = block_m + arow;
      if (gm < M) v = *(const uint4*)(A + (size_t)gm * FDIM + kk + cc);
      *(uint4*)(Asm + arow * 40 + cc) = v;
#pragma unroll
      for (int it = 0; it < 4; ++it) {
        int brow = it * 64 + arow;
        uint4 wv = *(const uint4*)(BT + (size_t)brow * FDIM + kk + cc);
        *(uint4*)(Bsm + brow * 40 + cc) = wv;
      }
    }
    __syncthreads();
    short8 af[4], bfr[4];
#pragma unroll
    for (int mt = 0; mt < 4; ++mt)
      af[mt] = *(const short8*)(Asm + (mt * 16 + rcol) * 40 + q * 8);
#pragma unroll
    for (int nt = 0; nt < 4; ++nt)
      bfr[nt] = *(const short8*)(Bsm + (wave * 64 + nt * 16 + rcol) * 40 + q * 8);
#pragma unroll
    for (int mt = 0; mt < 4; ++mt)
#pragma unroll
      for (int nt = 0; nt < 4; ++nt)
        acc[mt][nt] = __builtin_amdgcn_mfma_f32_16x16x32_bf16(af[mt], bfr[nt], acc[mt][nt], 0, 0, 0);
  }

  float bv[4];
#pragma unroll
  for (int nt = 0; nt < 4; ++nt) bv[nt] = bias[wave * 64 + nt * 16 + rcol];
#pragma unroll
  for (int mt = 0; mt < 4; ++mt)
#pragma unroll
    for (int rr = 0; rr < 4; ++rr) {
      int m = block_m + mt * 16 + q * 4 + rr;
      if (m >= M) continue;
      float sc = dis[m];
#pragma unroll
      for (int nt = 0; nt < 4; ++nt) {
        int nn = wave * 64 + nt * 16 + rcol;
        out[(size_t)m * FDIM + nn] = f2bf((acc[mt][nt][rr] + bv[nt]) * sc);
      }
    }
}

// ---------------- conv2 + head + log_softmax, fused; fp32 output ----------------
// l1s is pre-folded (l1*dis). xb = dis_i*(l1s[i] + sum l1s[src]); logits = xb @ Wc + bc

__global__ __launch_bounds__(256) void conv2_head_k(
    const unsigned short* __restrict__ l1, const int* __restrict__ row_ptr,
    const int* __restrict__ col, const float* __restrict__ dis,
    const float* __restrict__ Wc, const float* __restrict__ bc,
    float* __restrict__ out, int n) {
  __shared__ __align__(16) unsigned short Wsh[FDIM * FOUT];  // 20 KB bf16
  __shared__ __align__(16) float xsh[4][FDIM];               // 4 KB
  __shared__ float L[4][FOUT];
  __shared__ float bsh[FOUT];
  int t = threadIdx.x;
  for (int c = t; c < FDIM * FOUT / 4; c += 256) {
    float4 wv = ((const float4*)Wc)[c];
    ushort4 o;
    o.x = f2bf(wv.x); o.y = f2bf(wv.y); o.z = f2bf(wv.z); o.w = f2bf(wv.w);
    ((ushort4*)Wsh)[c] = o;
  }
  if (t < FOUT) bsh[t] = bc[t];
  int wave = t >> 6, lane = t & 63;
  int nd = t / 40, o = t - nd * 40;
  int step = gridDim.x * 4;
  for (int base = blockIdx.x * 4; base < n; base += step) {
    int i = base + wave;
    __syncthreads();
    if (i < n) {
      int f = lane * 4;
      ushort4 v = *(const ushort4*)(l1 + (size_t)i * FDIM + f);
      float a0 = bf2f(v.x), a1 = bf2f(v.y), a2 = bf2f(v.z), a3 = bf2f(v.w);
      int beg = row_ptr[i], end = row_ptr[i + 1];
      for (int j0 = beg; j0 < end; j0 += 64) {
        int jj = j0 + lane;
        int cs = (jj < end) ? col[jj] : 0;
        int cc = min(64, end - j0);
        for (int k = 0; k < cc; k += 8) {
          ushort4 g[8];
          float w[8];
#pragma unroll
          for (int u = 0; u < 8; ++u) {
            int ku = k + u;
            int s = __shfl(cs, ku & 63);
            w[u] = (ku < cc) ? 1.f : 0.f;
            g[u] = *(const ushort4*)(l1 + (size_t)s * FDIM + f);
          }
#pragma unroll
          for (int u = 0; u < 8; ++u) {
            a0 = fmaf(w[u], bf2f(g[u].x), a0);
            a1 = fmaf(w[u], bf2f(g[u].y), a1);
            a2 = fmaf(w[u], bf2f(g[u].z), a2);
            a3 = fmaf(w[u], bf2f(g[u].w), a3);
          }
        }
      }
      float di = dis[i];
      float4 xv = {a0 * di, a1 * di, a2 * di, a3 * di};
      *(float4*)&xsh[wave][f] = xv;
    }
    __syncthreads();
    if (t < 160) {
      float acc = bsh[o];
      for (int k = 0; k < FDIM; ++k)
        acc += xsh[nd][k] * bf2f(Wsh[k * FOUT + o]);
      L[nd][o] = acc;
    }
    __syncthreads();
    if (t < 4) {
      int gi = base + t;
      if (gi < n) {
        float m = -3.4e38f;
        for (int oo = 0; oo < FOUT; ++oo) m = fmaxf(m, L[t][oo]);
        float s = 0.f;
        for (int oo = 0; oo < FOUT; ++oo) s += __expf(L[t][oo] - m);
        float lg = m + __logf(s);
        for (int oo = 0; oo < FOUT; ++oo)
          out[(size_t)gi * FOUT + oo] = L[t][oo] - lg;
      }
    }
  }
}

// ---------------- launch ----------------

extern "C" void kernel_launch(void* const* d_in, const int* in_sizes, int n_in,
                              void* d_out, int out_size, void* d_ws, size_t ws_size,
                              hipStream_t stream) {
  const float* x   = (const float*)d_in[0];
  const int* eraw  = (const int*)d_in[1];
  const float* W1  = (const float*)d_in[2];
  const float* b1  = (const float*)d_in[3];
  const float* W2  = (const float*)d_in[4];
  const float* b2  = (const float*)d_in[5];
  const float* Wl  = (const float*)d_in[6];
  const float* bl  = (const float*)d_in[7];
  float* out = (float*)d_out;

  const int N = in_sizes[0] / FDIM;
  const int E = in_sizes[1] / 2;

  char* w = (char*)d_ws;
  size_t off = 0;
  auto take = [&](size_t bytes) {
    void* p = w + off;
    off = (off + bytes + 255) & ~(size_t)255;
    return p;
  };
  int* cnt     = (int*)take((size_t)N * 4);
  int* cursor  = (int*)take((size_t)N * 4);
  int* row_ptr = (int*)take((size_t)(N + 1) * 4);
  float* dis   = (float*)take((size_t)N * 4);
  int* bsum    = (int*)take(4096);
  int* eflag   = (int*)take(256);
  unsigned short* W1T = (unsigned short*)take((size_t)FDIM * FDIM * 2);
  float* Wc    = (float*)take((size_t)FDIM * FOUT * 4);
  float* bc    = (float*)take(FOUT * 4);
  int* colx    = (int*)take((size_t)E * 4);
  size_t pairBytes = (size_t)2 * E * 4;
  size_t bufBytes  = (size_t)N * FDIM * 2;
  size_t r1Bytes = bufBytes > pairBytes ? bufBytes : pairBytes;
  void* region1 = take(r1Bytes);
  unsigned short* buf = (unsigned short*)region1;
  // big path: xs (bf16 pre-folded x) lives in its own region, which also hosts srcN/dstN early
  size_t xsBytes = (size_t)N * FDIM * 2;
  size_t xsRegion = xsBytes > pairBytes ? xsBytes : pairBytes;
  bool big = (off + xsRegion) <= ws_size;
  unsigned short* xs = nullptr;
  int* srcN;
  if (big) {
    xs = (unsigned short*)take(xsRegion);
    srcN = (int*)xs;
  } else {
    srcN = (int*)region1;  // union with buf (dead before agg writes buf)
  }
  int* dstN = srcN + E;
  (void)n_in; (void)out_size;

  int gE = (E + 255) / 256;
  int gN = (N + 255) / 256;
  int NB = (N + 1023) / 1024;
  int gG = (N + 63) / 64;

  int probe_words = 65536 < 2 * E ? 65536 : 2 * E;
  hipLaunchKernelGGL(detect_k, dim3(1), dim3(256), 0, stream, eraw, probe_words, eflag);
  hipLaunchKernelGGL(normalize_k, dim3(gE), dim3(256), 0, stream, eraw, eflag, srcN, dstN, E);

  hipLaunchKernelGGL(zero_cnt_k, dim3(gN), dim3(256), 0, stream, cnt, N);
  hipLaunchKernelGGL(count_k, dim3(gE), dim3(256), 0, stream, dstN, cnt, E, N);
  hipLaunchKernelGGL(dis_k, dim3(gN), dim3(256), 0, stream, cnt, dis, N);
  hipLaunchKernelGGL(scan_a_k, dim3(NB), dim3(1024), 0, stream, cnt, row_ptr, bsum, N);
  hipLaunchKernelGGL(scan_b_k, dim3(1), dim3(1024), 0, stream, bsum, NB);
  hipLaunchKernelGGL(scan_c_k, dim3(NB), dim3(1024), 0, stream, row_ptr, bsum, cnt, cursor, N);
  hipLaunchKernelGGL(fill_k, dim3(gE), dim3(256), 0, stream, srcN, dstN, cursor, colx, E, N);
  hipLaunchKernelGGL(transp_k, dim3(FDIM), dim3(FDIM), 0, stream, W1, W1T);
  hipLaunchKernelGGL(wc_k, dim3(FDIM), dim3(64), 0, stream, W2, Wl, Wc);
  hipLaunchKernelGGL(bc_k, dim3(1), dim3(64), 0, stream, b2, Wl, bl, bc);

  // layer 1: z = dis_i*(sum of pre-folded rows); in-place GEMM folds bias and dis for layer 2
  if (big) {
    hipLaunchKernelGGL(fold_k, dim3(2048), dim3(256), 0, stream, x, dis, xs, N);
    hipLaunchKernelGGL(agg_b_k, dim3(2048), dim3(256), 0, stream,
                       xs, row_ptr, colx, dis, buf, N);
  } else {
    hipLaunchKernelGGL(agg_f_k, dim3(2048), dim3(256), 0, stream,
                       x, row_ptr, colx, dis, buf, N);
  }
  hipLaunchKernelGGL(gemm_bias_k, dim3(gG), dim3(256), 0, stream, buf, W1T, b1, dis, buf, N);
  hipLaunchKernelGGL(conv2_head_k, dim3(2048), dim3(256), 0, stream,
                     buf, row_ptr, colx, dis, Wc, bc, out, N);
}